// Round 15
// baseline (1036.169 us; speedup 1.0000x reference)
//
#include <hip/hip_runtime.h>
#include <hip/hip_bf16.h>
#include <stdint.h>

#define NTOK 8192
#define DDIM 1024
#define HDIM 4096
#define NEXP 8
#define MAXWL1 48   // BM=256 work-list
#define MAXWL2 72   // BM=128 work-list

typedef __attribute__((ext_vector_type(4))) float f32x4;
typedef __attribute__((ext_vector_type(8))) short s16x8;
typedef __attribute__((ext_vector_type(8))) unsigned short u16x8;

__device__ __forceinline__ unsigned short f2bf(float f) {
  union { float f; unsigned int u; } v; v.f = f;
  unsigned int u = v.u;
  u += 0x7FFFu + ((u >> 16) & 1u);   // round-to-nearest-even
  return (unsigned short)(u >> 16);
}

typedef __attribute__((address_space(3))) unsigned char lds_u8;
typedef const __attribute__((address_space(1))) unsigned char glb_u8;

__device__ __forceinline__ void load_lds16(const void* g, void* l) {
  __builtin_amdgcn_global_load_lds((glb_u8*)g, (lds_u8*)l, 16, 0, 0);
}

// ---------------- gate + top-1 routing ----------------
__global__ __launch_bounds__(256) void gate_kernel(
    const float* __restrict__ x, const float* __restrict__ Wg,
    const float* __restrict__ bg, int* __restrict__ counts,
    int* __restrict__ lists) {
  const int lane = threadIdx.x & 63;
  const int tok = blockIdx.x * 4 + (threadIdx.x >> 6);
  const float* xr = x + (size_t)tok * DDIM;
  double acc[NEXP];
#pragma unroll
  for (int e = 0; e < NEXP; ++e) acc[e] = 0.0;
#pragma unroll 4
  for (int it = 0; it < DDIM / 64; ++it) {
    const int d = it * 64 + lane;
    const float xv = xr[d];
    const f32x4 w0 = *(const f32x4*)(Wg + (size_t)d * NEXP);
    const f32x4 w1 = *(const f32x4*)(Wg + (size_t)d * NEXP + 4);
#pragma unroll
    for (int j = 0; j < 4; ++j) {
      acc[j]     += (double)xv * (double)w0[j];
      acc[4 + j] += (double)xv * (double)w1[j];
    }
  }
#pragma unroll
  for (int e = 0; e < NEXP; ++e) {
    double v = acc[e];
#pragma unroll
    for (int off = 32; off > 0; off >>= 1) v += __shfl_xor(v, off, 64);
    acc[e] = v;
  }
  if (lane == 0) {
    int best = 0;
    double bv = acc[0] + (double)bg[0];
#pragma unroll
    for (int e = 1; e < NEXP; ++e) {
      const double v = acc[e] + (double)bg[e];
      if (v > bv) { bv = v; best = e; }   // strict > : first max wins (np argmax)
    }
    const int pos = atomicAdd(&counts[best], 1);
    lists[best * NTOK + pos] = tok;
  }
}

// ---- prefix sum + two work-lists: wl1 (BM=256), wl2 (BM=128) ----
__global__ void offs_kernel(const int* __restrict__ counts, int* __restrict__ offs,
                            int* __restrict__ wl1, int* __restrict__ wl2) {
  int s = 0;
#pragma unroll
  for (int e = 0; e < NEXP; ++e) { offs[e] = s; s += counts[e]; }
  offs[NEXP] = s;
  int n1 = 0, n2 = 0;
  for (int e = 0; e < NEXP; ++e) {
    const int nb1 = (counts[e] + 255) >> 8;
    for (int b = 0; b < nb1; ++b) wl1[n1++] = (e << 20) | b;
    const int nb2 = (counts[e] + 127) >> 7;
    for (int b = 0; b < nb2; ++b) wl2[n2++] = (e << 20) | b;
  }
  offs[NEXP + 1] = n1;
  offs[NEXP + 2] = n2;
}

// -------- gather tokens into expert-sorted order, convert to bf16 --------
__global__ __launch_bounds__(256) void gather_conv_kernel(
    const float* __restrict__ x, const int* __restrict__ offs,
    const int* __restrict__ lists, int* __restrict__ stok,
    unsigned short* __restrict__ xbs) {
  const int p = blockIdx.x * 4 + (threadIdx.x >> 6);   // sorted position
  const int lane = threadIdx.x & 63;
  int e = 0;
#pragma unroll
  for (int k = 1; k < NEXP; ++k) e += (p >= offs[k]) ? 1 : 0;
  const int tok = lists[e * NTOK + (p - offs[e])];
  if (lane == 0) stok[p] = tok;
  const float* src = x + (size_t)tok * DDIM + lane * 16;
  unsigned short* dst = xbs + (size_t)p * DDIM + lane * 16;
#pragma unroll
  for (int q = 0; q < 2; ++q) {
    const f32x4 a = *(const f32x4*)(src + q * 8);
    const f32x4 b = *(const f32x4*)(src + q * 8 + 4);
    u16x8 o;
#pragma unroll
    for (int j = 0; j < 4; ++j) { o[j] = f2bf(a[j]); o[4 + j] = f2bf(b[j]); }
    *(u16x8*)(dst + q * 8) = o;
  }
}

// ---- grouped GEMM with FUSED B transpose+convert (no weight prep kernels) ----
// A: bf16 [NTOK][K] expert-sorted rows (gload_lds, ring-3, swizzled source).
// B: fp32 [E][K][N] row-major (W1:[D][H], W2:[H][D] — both are [K][N]!).
//   Per K-tile, thread owns (col, k-slot q): 8 coalesced dword loads
//   (k-run strided N, lanes cover consecutive cols -> 256B/wave chunks),
//   cvt fp32->bf16, ONE ds_write_b128 into swizzled [BN][32] layout.
//   Write slot = q ^ ((col>>1)&3) == read swizzle  (bank-checked: quarter-wave
//   covers all 8 groups x2 -> free).
// Schedule (depth-1, R10-proven at 2 blk/CU): per iter t:
//   vmcnt(0)  [A(t+1) DMA landed, B(t+1) dwords in regs]
//   lgkmcnt(0); barrier   [B-write(t) retired block-wide]
//   ds_read tile t (A[t%3], B[t%2]) -> frags
//   writeB(t+1) -> B[(t+1)%2]   [buffer read at t-1, retired]
//   stageA(t+2) -> A[(t+2)%3]; loadB(t+2) -> regs   [A buf read at t-1, retired]
//   setprio(1); 16 MFMA; setprio(0)
template <int BM, int BN, int WM, int WN, int K, int N, int MAXWLT,
          bool COLFAST, bool FUSE1>
__global__ __launch_bounds__(512, 4) void ffn_kernel(
    const unsigned short* __restrict__ A, const float* __restrict__ Wf,
    const float* __restrict__ bias, const int* __restrict__ counts,
    const int* __restrict__ offs, const int* __restrict__ wl,
    const int* __restrict__ stok, unsigned short* __restrict__ outb,
    float* __restrict__ outf, int nwl_idx) {
  constexpr int MF = BM / (WM * 16);   // 4
  constexpr int NF = BN / (WN * 16);   // 4
  constexpr int ISS_A = BM / 128;
  constexpr int NRUN = BN / 128;       // B col-runs per thread
  constexpr int NT = K / 32;
  constexpr int NCB = N / BN;
  constexpr int NWG = NCB * MAXWLT;
  static_assert((NWG & 7) == 0 && (NT % 6) == 2 && NT >= 8, "");
  static_assert(WM * WN == 8, "8 waves");

  const int d = blockIdx.x;
  const int logical = (d & 7) * (NWG / 8) + (d >> 3);  // XCD chunking
  int cb, wli;
  if constexpr (COLFAST) { cb = logical % NCB; wli = logical / NCB; }
  else                   { cb = logical / MAXWLT; wli = logical % MAXWLT; }
  if (wli >= offs[nwl_idx]) return;
  const int col0 = cb * BN;
  const int wle = wl[wli];
  const int e = wle >> 20;
  const int bx = wle & 0xFFFFF;
  const int cnt = counts[e];
  const int row0 = offs[e] + bx * BM;

  __shared__ __align__(16) unsigned short A0[BM * 32], A1[BM * 32], A2[BM * 32];
  __shared__ __align__(16) unsigned short B0[BN * 32], B1[BN * 32];

  const int tid = threadIdx.x;
  const int lane = tid & 63;
  const int w = tid >> 6;
  const int wm = w / WN;
  const int wn = w % WN;
  const int fr = lane & 15;
  const int fj = lane >> 4;

  // ---- A staging (gload_lds, pre-swizzled source; R9-verified 0-conflict) ----
  const int swsrc = ((tid & 3) ^ ((tid >> 3) & 3)) * 8;   // ushort offset
  const int rbA = tid >> 2;
  const unsigned short* srcA[ISS_A];
#pragma unroll
  for (int i = 0; i < ISS_A; ++i) {
    int gr = row0 + i * 128 + rbA;
    if (gr > NTOK - 1) gr = NTOK - 1;   // clamp: garbage rows masked in epilogue
    srcA[i] = A + (size_t)gr * K + swsrc;
  }
  auto stageA = [&](unsigned short* dA, int kel) {
#pragma unroll
    for (int i = 0; i < ISS_A; ++i)
      load_lds16(srcA[i] + kel, dA + i * 4096 + tid * 8);
  };

  // ---- B staging (fused transpose+convert) ----
  const int cl = tid & 127;       // column within 128-run
  const int q  = tid >> 7;        // k-slot 0..3 (k = 8q..8q+7)
  const float* Wfe = Wf + (size_t)e * K * N;
  float bregs[NRUN * 8];
  auto loadB = [&](int kel) {
#pragma unroll
    for (int i = 0; i < NRUN; ++i) {
      const float* bp = Wfe + (size_t)(kel + 8 * q) * N + col0 + 128 * i + cl;
#pragma unroll
      for (int j = 0; j < 8; ++j) bregs[i * 8 + j] = bp[(size_t)j * N];
    }
  };
  auto writeB = [&](unsigned short* dB) {
#pragma unroll
    for (int i = 0; i < NRUN; ++i) {
      u16x8 o;
#pragma unroll
      for (int j = 0; j < 8; ++j) o[j] = f2bf(bregs[i * 8 + j]);
      const int row = 128 * i + cl;
      const int slot = q ^ ((row >> 1) & 3);
      *(u16x8*)(dB + row * 32 + slot * 8) = o;
    }
  };

  // ds_read swizzled 16B-slot (per-lane constant): fj ^ ((fr>>1)&3)
  const int js = (fj ^ ((fr >> 1) & 3)) * 8;

  f32x4 acc[MF][NF];
#pragma unroll
  for (int m = 0; m < MF; ++m)
#pragma unroll
    for (int n = 0; n < NF; ++n) acc[m][n] = f32x4{0.f, 0.f, 0.f, 0.f};

  auto body = [&](const unsigned short* pA, const unsigned short* pB,
                  unsigned short* nA, int kissue, unsigned short* wB,
                  bool dow, bool doi) {
    asm volatile("s_waitcnt vmcnt(0)" ::: "memory");   // A(t+1) landed, B(t+1) regs in
    asm volatile("s_waitcnt lgkmcnt(0)" ::: "memory"); // B-write(t) retired
    __builtin_amdgcn_s_barrier();
    asm volatile("" ::: "memory");
    s16x8 af[MF], bf[NF];
#pragma unroll
    for (int m = 0; m < MF; ++m)
      af[m] = *(const s16x8*)(pA + (wm * MF * 16 + m * 16 + fr) * 32 + js);
#pragma unroll
    for (int n = 0; n < NF; ++n)
      bf[n] = *(const s16x8*)(pB + (wn * NF * 16 + n * 16 + fr) * 32 + js);
    if (dow) writeB(wB);                    // tile t+1 -> other B buffer
    if (doi) { stageA(nA, kissue); loadB(kissue); }   // tile t+2
    __builtin_amdgcn_s_setprio(1);
#pragma unroll
    for (int m = 0; m < MF; ++m)
#pragma unroll
      for (int n = 0; n < NF; ++n)
        acc[m][n] = __builtin_amdgcn_mfma_f32_16x16x32_bf16(af[m], bf[n],
                                                            acc[m][n], 0, 0, 0);
    __builtin_amdgcn_s_setprio(0);
  };

  // prologue: tile0 staged+written, tile1 in flight
  stageA(A0, 0); loadB(0);
  asm volatile("s_waitcnt vmcnt(0)" ::: "memory");
  writeB(B0);
  stageA(A1, 32); loadB(32);

#pragma unroll 1
  for (int t = 0; t < NT - 2; t += 6) {   // NT % 6 == 2
    body(A0, B0, A2, (t + 2) * 32, B1, true, true);
    body(A1, B1, A0, (t + 3) * 32, B0, true, true);
    body(A2, B0, A1, (t + 4) * 32, B1, true, true);
    body(A0, B1, A2, (t + 5) * 32, B0, true, true);
    body(A1, B0, A0, (t + 6) * 32, B1, true, true);
    body(A2, B1, A1, (t + 7) * 32, B0, true, true);
  }
  // remainder: tiles NT-2 ((NT-2)%3==0, %2==0), NT-1
  body(A0, B0, nullptr, 0, B1, true, false);
  body(A1, B1, nullptr, 0, nullptr, false, false);

  // epilogue
#pragma unroll
  for (int n = 0; n < NF; ++n) {
    const int col = col0 + wn * NF * 16 + n * 16 + fr;
    const float bv = bias[e * N + col];
#pragma unroll
    for (int m = 0; m < MF; ++m) {
#pragma unroll
      for (int j = 0; j < 4; ++j) {
        const int rl = wm * MF * 16 + m * 16 + fj * 4 + j;
        if (bx * BM + rl < cnt) {
          if constexpr (FUSE1) {
            outb[(size_t)(row0 + rl) * N + col] = f2bf(fmaxf(acc[m][n][j] + bv, 0.f));
          } else {
            outf[(size_t)stok[row0 + rl] * N + col] = acc[m][n][j] + bv;
          }
        }
      }
    }
  }
}

extern "C" void kernel_launch(void* const* d_in, const int* in_sizes, int n_in,
                              void* d_out, int out_size, void* d_ws, size_t ws_size,
                              hipStream_t stream) {
  (void)in_sizes; (void)n_in; (void)out_size;
  const float* x  = (const float*)d_in[0];
  const float* Wg = (const float*)d_in[1];
  const float* bg = (const float*)d_in[2];
  const float* W1 = (const float*)d_in[3];
  const float* b1 = (const float*)d_in[4];
  const float* W2 = (const float*)d_in[5];
  const float* b2 = (const float*)d_in[6];
  float* out = (float*)d_out;

  char* ws = (char*)d_ws;
  const size_t OFF_CNT = 0;                                    // 8 ints
  const size_t OFF_OFF = 128;                                  // offs[0..10]
  const size_t OFF_WL1 = 256;                                  // MAXWL1 ints
  const size_t OFF_WL2 = 256 + MAXWL1 * 4;                     // MAXWL2 ints
  const size_t OFF_LST = 1024;                                 // E*NTOK ints (256 KB)
  const size_t OFF_STK = OFF_LST + (size_t)NEXP * NTOK * 4;    // NTOK ints
  const size_t OFF_XBS = OFF_STK + (size_t)NTOK * 4;           // NTOK*D bf16 (16 MB)
  const size_t OFF_HS  = OFF_XBS + (size_t)NTOK * DDIM * 2;    // NTOK*H bf16 (64 MB)
  const size_t NEED    = OFF_HS + (size_t)NTOK * HDIM * 2;
  if (ws_size < NEED) return;

  int* counts = (int*)(ws + OFF_CNT);
  int* offs   = (int*)(ws + OFF_OFF);
  int* wl1    = (int*)(ws + OFF_WL1);
  int* wl2    = (int*)(ws + OFF_WL2);
  int* lists  = (int*)(ws + OFF_LST);
  int* stok   = (int*)(ws + OFF_STK);
  unsigned short* xbs = (unsigned short*)(ws + OFF_XBS);
  unsigned short* Hs  = (unsigned short*)(ws + OFF_HS);

  hipMemsetAsync(counts, 0, 128, stream);
  gate_kernel<<<NTOK / 4, 256, 0, stream>>>(x, Wg, bg, counts, lists);
  offs_kernel<<<1, 1, 0, stream>>>(counts, offs, wl1, wl2);
  gather_conv_kernel<<<NTOK / 4, 256, 0, stream>>>(x, offs, lists, stok, xbs);

  // ffn1: 256x128 tile, B = W1 fp32 [D][H] fused-transposed; wli-fastest
  ffn_kernel<256, 128, 4, 2, DDIM, HDIM, MAXWL1, false, true>
      <<<dim3((HDIM / 128) * MAXWL1), 512, 0, stream>>>(
          xbs, W1, b1, counts, offs, wl1, stok, Hs, nullptr, NEXP + 1);
  // ffn2: 128x256 tile, B = W2 fp32 [H][D] fused-transposed; col-fastest
  ffn_kernel<128, 256, 2, 4, HDIM, DDIM, MAXWL2, true, false>
      <<<dim3((DDIM / 256) * MAXWL2), 512, 0, stream>>>(
          Hs, W2, b2, counts, offs, wl2, stok, nullptr, out, NEXP + 2);
}

// Round 16
// 466.275 us; speedup vs baseline: 2.2222x; 2.2222x over previous
//
#include <hip/hip_runtime.h>
#include <hip/hip_bf16.h>
#include <stdint.h>

#define NTOK 8192
#define DDIM 1024
#define HDIM 4096
#define NEXP 8
#define MAXWL1 48   // BM=256 work-list
#define MAXWL2 72   // BM=128 work-list

typedef __attribute__((ext_vector_type(4))) float f32x4;
typedef __attribute__((ext_vector_type(8))) short s16x8;
typedef __attribute__((ext_vector_type(8))) unsigned short u16x8;

__device__ __forceinline__ unsigned short f2bf(float f) {
  union { float f; unsigned int u; } v; v.f = f;
  unsigned int u = v.u;
  u += 0x7FFFu + ((u >> 16) & 1u);   // round-to-nearest-even
  return (unsigned short)(u >> 16);
}

typedef __attribute__((address_space(3))) unsigned char lds_u8;
typedef const __attribute__((address_space(1))) unsigned char glb_u8;

__device__ __forceinline__ void load_lds16(const void* g, void* l) {
  __builtin_amdgcn_global_load_lds((glb_u8*)g, (lds_u8*)l, 16, 0, 0);
}

// ---------------- gate + top-1 routing ----------------
__global__ __launch_bounds__(256) void gate_kernel(
    const float* __restrict__ x, const float* __restrict__ Wg,
    const float* __restrict__ bg, int* __restrict__ counts,
    int* __restrict__ lists) {
  const int lane = threadIdx.x & 63;
  const int tok = blockIdx.x * 4 + (threadIdx.x >> 6);
  const float* xr = x + (size_t)tok * DDIM;
  double acc[NEXP];
#pragma unroll
  for (int e = 0; e < NEXP; ++e) acc[e] = 0.0;
#pragma unroll 4
  for (int it = 0; it < DDIM / 64; ++it) {
    const int d = it * 64 + lane;
    const float xv = xr[d];
    const f32x4 w0 = *(const f32x4*)(Wg + (size_t)d * NEXP);
    const f32x4 w1 = *(const f32x4*)(Wg + (size_t)d * NEXP + 4);
#pragma unroll
    for (int j = 0; j < 4; ++j) {
      acc[j]     += (double)xv * (double)w0[j];
      acc[4 + j] += (double)xv * (double)w1[j];
    }
  }
#pragma unroll
  for (int e = 0; e < NEXP; ++e) {
    double v = acc[e];
#pragma unroll
    for (int off = 32; off > 0; off >>= 1) v += __shfl_xor(v, off, 64);
    acc[e] = v;
  }
  if (lane == 0) {
    int best = 0;
    double bv = acc[0] + (double)bg[0];
#pragma unroll
    for (int e = 1; e < NEXP; ++e) {
      const double v = acc[e] + (double)bg[e];
      if (v > bv) { bv = v; best = e; }   // strict > : first max wins (np argmax)
    }
    const int pos = atomicAdd(&counts[best], 1);
    lists[best * NTOK + pos] = tok;
  }
}

// ---- prefix sum + two work-lists: wl1 (BM=256), wl2 (BM=128) ----
__global__ void offs_kernel(const int* __restrict__ counts, int* __restrict__ offs,
                            int* __restrict__ wl1, int* __restrict__ wl2) {
  int s = 0;
#pragma unroll
  for (int e = 0; e < NEXP; ++e) { offs[e] = s; s += counts[e]; }
  offs[NEXP] = s;
  int n1 = 0, n2 = 0;
  for (int e = 0; e < NEXP; ++e) {
    const int nb1 = (counts[e] + 255) >> 8;
    for (int b = 0; b < nb1; ++b) wl1[n1++] = (e << 20) | b;
    const int nb2 = (counts[e] + 127) >> 7;
    for (int b = 0; b < nb2; ++b) wl2[n2++] = (e << 20) | b;
  }
  offs[NEXP + 1] = n1;
  offs[NEXP + 2] = n2;
}

// -------- gather tokens into expert-sorted order, convert to bf16 --------
__global__ __launch_bounds__(256) void gather_conv_kernel(
    const float* __restrict__ x, const int* __restrict__ offs,
    const int* __restrict__ lists, int* __restrict__ stok,
    unsigned short* __restrict__ xbs) {
  const int p = blockIdx.x * 4 + (threadIdx.x >> 6);   // sorted position
  const int lane = threadIdx.x & 63;
  int e = 0;
#pragma unroll
  for (int k = 1; k < NEXP; ++k) e += (p >= offs[k]) ? 1 : 0;
  const int tok = lists[e * NTOK + (p - offs[e])];
  if (lane == 0) stok[p] = tok;
  const float* src = x + (size_t)tok * DDIM + lane * 16;
  unsigned short* dst = xbs + (size_t)p * DDIM + lane * 16;
#pragma unroll
  for (int q = 0; q < 2; ++q) {
    const f32x4 a = *(const f32x4*)(src + q * 8);
    const f32x4 b = *(const f32x4*)(src + q * 8 + 4);
    u16x8 o;
#pragma unroll
    for (int j = 0; j < 4; ++j) { o[j] = f2bf(a[j]); o[4 + j] = f2bf(b[j]); }
    *(u16x8*)(dst + q * 8) = o;
  }
}

// -- transpose + convert tile body (R10 v2): 64x64 tile, 16B writes --
__device__ __forceinline__ void transpose_tile(
    const float* __restrict__ ine, unsigned short* __restrict__ oute,
    int R, int C, int c0, int r0, int t) {
  __shared__ unsigned short T[64][66];
  const int tr = t >> 4, tc4 = (t & 15) * 4;
#pragma unroll
  for (int p = 0; p < 4; ++p) {
    const int r = tr + p * 16;
    const f32x4 v = *(const f32x4*)(ine + (size_t)(r0 + r) * C + c0 + tc4);
#pragma unroll
    for (int j = 0; j < 4; ++j) T[r][tc4 + j] = f2bf(v[j]);
  }
  __syncthreads();
  const int cc = t >> 3, rr8 = (t & 7) * 8;
#pragma unroll
  for (int p = 0; p < 2; ++p) {
    const int c = cc + p * 32;
    u16x8 o;
#pragma unroll
    for (int j = 0; j < 8; ++j) o[j] = T[rr8 + j][c];
    *(u16x8*)(oute + (size_t)(c0 + c) * R + r0 + rr8) = o;
  }
}

// -- single-weight transpose launch (fallback path): [E][R][C] -> [E][C][R] --
__global__ __launch_bounds__(256) void transpose_conv_kernel(
    const float* __restrict__ in, unsigned short* __restrict__ out,
    int R, int C) {
  const int e = blockIdx.z;
  transpose_tile(in + (size_t)e * R * C, out + (size_t)e * C * R, R, C,
                 blockIdx.x * 64, blockIdx.y * 64, threadIdx.x);
}

// -- merged both-weights transpose: 1D exact grid, no dead blocks --
// id < 8192: W1 (R=DDIM,C=HDIM); else W2 (R=HDIM,C=DDIM). 1024 blocks/expert.
__global__ __launch_bounds__(256) void transpose_conv2_kernel(
    const float* __restrict__ W1, const float* __restrict__ W2,
    unsigned short* __restrict__ Wt1, unsigned short* __restrict__ Wt2) {
  const int id = blockIdx.x;
  if (id < 8192) {
    const int e = id >> 10, rem = id & 1023;
    const int cb = rem & 63, rb = rem >> 6;     // C=4096: 64 c-tiles; R=1024: 16
    transpose_tile(W1 + (size_t)e * DDIM * HDIM, Wt1 + (size_t)e * HDIM * DDIM,
                   DDIM, HDIM, cb * 64, rb * 64, threadIdx.x);
  } else {
    const int id2 = id - 8192;
    const int e = id2 >> 10, rem = id2 & 1023;
    const int cb = rem & 15, rb = rem >> 4;     // C=1024: 16 c-tiles; R=4096: 64
    transpose_tile(W2 + (size_t)e * HDIM * DDIM, Wt2 + (size_t)e * DDIM * HDIM,
                   HDIM, DDIM, cb * 64, rb * 64, threadIdx.x);
  }
}

// ---- grouped GEMM: R10 exact — ring-2, depth-1, 2 blk/CU, 0-conflict swizzle ----
// A: bf16 [NTOK][K] expert-sorted rows. Bt: bf16 [E][N][K] (K-contiguous rows).
// Per-wave 64x64 output (acc 64 VGPR -> 2 blk/CU). Phase: vmcnt(0)+barrier ->
// 8x ds_read -> stage next tile (flies under MFMA + co-resident block) -> 16 MFMA.
template <int BM, int BN, int WM, int WN, int K, int N, int MAXWLT,
          bool COLFAST, bool FUSE1>
__global__ __launch_bounds__(512, 4) void ffn_kernel(
    const unsigned short* __restrict__ A, const unsigned short* __restrict__ Bt,
    const float* __restrict__ bias, const int* __restrict__ counts,
    const int* __restrict__ offs, const int* __restrict__ wl,
    const int* __restrict__ stok, unsigned short* __restrict__ outb,
    float* __restrict__ outf, int nwl_idx) {
  constexpr int MF = BM / (WM * 16);   // 4
  constexpr int NF = BN / (WN * 16);   // 4
  constexpr int ISS_A = BM / 128;
  constexpr int ISS_B = BN / 128;
  constexpr int NT = K / 32;
  constexpr int NCB = N / BN;
  constexpr int NWG = NCB * MAXWLT;
  static_assert((NWG & 7) == 0 && (NT & 1) == 0 && NT >= 4, "");
  static_assert(WM * WN == 8, "8 waves");

  const int d = blockIdx.x;
  const int logical = (d & 7) * (NWG / 8) + (d >> 3);  // XCD chunking
  int cb, wli;
  if constexpr (COLFAST) { cb = logical % NCB; wli = logical / NCB; }
  else                   { cb = logical / MAXWLT; wli = logical % MAXWLT; }
  if (wli >= offs[nwl_idx]) return;
  const int col0 = cb * BN;
  const int wle = wl[wli];
  const int e = wle >> 20;
  const int bx = wle & 0xFFFFF;
  const int cnt = counts[e];
  const int row0 = offs[e] + bx * BM;

  __shared__ __align__(16) unsigned short As0[BM * 32], Bs0[BN * 32];
  __shared__ __align__(16) unsigned short As1[BM * 32], Bs1[BN * 32];

  const int tid = threadIdx.x;
  const int lane = tid & 63;
  const int w = tid >> 6;
  const int wm = w / WN;
  const int wn = w % WN;
  const int fr = lane & 15;
  const int fj = lane >> 4;

  // staging: thread -> LDS row i*128+(tid>>2), 16B-slot tid&3;
  // source slot pre-swizzled by ^((row>>1)&3) = ^((tid>>3)&3)  [R9-verified]
  const int swsrc = ((tid & 3) ^ ((tid >> 3) & 3)) * 8;   // ushort offset
  const int rb = tid >> 2;
  const unsigned short* srcA[ISS_A];
#pragma unroll
  for (int i = 0; i < ISS_A; ++i) {
    int gr = row0 + i * 128 + rb;
    if (gr > NTOK - 1) gr = NTOK - 1;   // clamp: garbage rows masked in epilogue
    srcA[i] = A + (size_t)gr * K + swsrc;
  }
  const unsigned short* Bte = Bt + (size_t)e * N * K;
  const unsigned short* srcB[ISS_B];
#pragma unroll
  for (int i = 0; i < ISS_B; ++i)
    srcB[i] = Bte + (size_t)(col0 + i * 128 + rb) * K + swsrc;

  // ds_read swizzled 16B-slot (per-lane constant): fj ^ ((fr>>1)&3)
  const int js = (fj ^ ((fr >> 1) & 3)) * 8;

  f32x4 acc[MF][NF];
#pragma unroll
  for (int m = 0; m < MF; ++m)
#pragma unroll
    for (int n = 0; n < NF; ++n) acc[m][n] = f32x4{0.f, 0.f, 0.f, 0.f};

  auto stage = [&](unsigned short* dA, unsigned short* dB, int kel) {
#pragma unroll
    for (int i = 0; i < ISS_A; ++i)
      load_lds16(srcA[i] + kel, dA + i * 4096 + tid * 8);
#pragma unroll
    for (int i = 0; i < ISS_B; ++i)
      load_lds16(srcB[i] + kel, dB + i * 4096 + tid * 8);
  };

  auto phase = [&](const unsigned short* pA, const unsigned short* pB,
                   unsigned short* nA, unsigned short* nB, int knext,
                   bool do_stage) {
    asm volatile("s_waitcnt vmcnt(0)" ::: "memory");  // current tile landed
    __builtin_amdgcn_s_barrier();
    asm volatile("" ::: "memory");
    // read whole tile into registers BEFORE staging next (no alias waits)
    s16x8 af[MF], bf[NF];
#pragma unroll
    for (int m = 0; m < MF; ++m)
      af[m] = *(const s16x8*)(pA + (wm * MF * 16 + m * 16 + fr) * 32 + js);
#pragma unroll
    for (int n = 0; n < NF; ++n)
      bf[n] = *(const s16x8*)(pB + (wn * NF * 16 + n * 16 + fr) * 32 + js);
    if (do_stage) stage(nA, nB, knext);   // flies under MFMA + co-resident block
    __builtin_amdgcn_s_setprio(1);
#pragma unroll
    for (int m = 0; m < MF; ++m)
#pragma unroll
      for (int n = 0; n < NF; ++n)
        acc[m][n] = __builtin_amdgcn_mfma_f32_16x16x32_bf16(af[m], bf[n],
                                                            acc[m][n], 0, 0, 0);
    __builtin_amdgcn_s_setprio(0);
  };

  stage(As0, Bs0, 0);   // prologue
#pragma unroll 1
  for (int t = 0; t < NT - 2; t += 2) {
    phase(As0, Bs0, As1, Bs1, (t + 1) * 32, true);
    phase(As1, Bs1, As0, Bs0, (t + 2) * 32, true);
  }
  phase(As0, Bs0, As1, Bs1, (NT - 1) * 32, true);
  phase(As1, Bs1, nullptr, nullptr, 0, false);

  // epilogue
#pragma unroll
  for (int n = 0; n < NF; ++n) {
    const int col = col0 + wn * NF * 16 + n * 16 + fr;
    const float bv = bias[e * N + col];
#pragma unroll
    for (int m = 0; m < MF; ++m) {
#pragma unroll
      for (int j = 0; j < 4; ++j) {
        const int rl = wm * MF * 16 + m * 16 + fj * 4 + j;
        if (bx * BM + rl < cnt) {
          if constexpr (FUSE1) {
            outb[(size_t)(row0 + rl) * N + col] = f2bf(fmaxf(acc[m][n][j] + bv, 0.f));
          } else {
            outf[(size_t)stok[row0 + rl] * N + col] = acc[m][n][j] + bv;
          }
        }
      }
    }
  }
}

extern "C" void kernel_launch(void* const* d_in, const int* in_sizes, int n_in,
                              void* d_out, int out_size, void* d_ws, size_t ws_size,
                              hipStream_t stream) {
  (void)in_sizes; (void)n_in; (void)out_size;
  const float* x  = (const float*)d_in[0];
  const float* Wg = (const float*)d_in[1];
  const float* bg = (const float*)d_in[2];
  const float* W1 = (const float*)d_in[3];
  const float* b1 = (const float*)d_in[4];
  const float* W2 = (const float*)d_in[5];
  const float* b2 = (const float*)d_in[6];
  float* out = (float*)d_out;

  char* ws = (char*)d_ws;
  const size_t OFF_CNT = 0;                                    // 8 ints
  const size_t OFF_OFF = 128;                                  // offs[0..10]
  const size_t OFF_WL1 = 256;                                  // MAXWL1 ints
  const size_t OFF_WL2 = 256 + MAXWL1 * 4;                     // MAXWL2 ints
  const size_t OFF_LST = 1024;                                 // E*NTOK ints (256 KB)
  const size_t OFF_STK = OFF_LST + (size_t)NEXP * NTOK * 4;    // NTOK ints
  const size_t OFF_XBS = OFF_STK + (size_t)NTOK * 4;           // NTOK*D bf16 (16 MB)
  const size_t OFF_HS  = OFF_XBS + (size_t)NTOK * DDIM * 2;    // NTOK*H bf16 (64 MB)
  const size_t OFF_WT1 = OFF_HS + (size_t)NTOK * HDIM * 2;     // E*H*D bf16 (64 MB)
  const size_t SZ_W    = (size_t)NEXP * DDIM * HDIM * 2;
  const size_t OFF_WT2 = OFF_WT1 + SZ_W;                       // E*D*H bf16 (64 MB)
  const size_t NEED_SMALL = OFF_WT1 + SZ_W;                    // shared Wt buffer
  const size_t NEED_BIG   = OFF_WT2 + SZ_W;                    // both Wt buffers
  if (ws_size < NEED_SMALL) return;
  const bool big = (ws_size >= NEED_BIG);

  int* counts = (int*)(ws + OFF_CNT);
  int* offs   = (int*)(ws + OFF_OFF);
  int* wl1    = (int*)(ws + OFF_WL1);
  int* wl2    = (int*)(ws + OFF_WL2);
  int* lists  = (int*)(ws + OFF_LST);
  int* stok   = (int*)(ws + OFF_STK);
  unsigned short* xbs = (unsigned short*)(ws + OFF_XBS);
  unsigned short* Hs  = (unsigned short*)(ws + OFF_HS);
  unsigned short* Wt1 = (unsigned short*)(ws + OFF_WT1);
  unsigned short* Wt2 = big ? (unsigned short*)(ws + OFF_WT2) : Wt1;

  hipMemsetAsync(counts, 0, 128, stream);
  gate_kernel<<<NTOK / 4, 256, 0, stream>>>(x, Wg, bg, counts, lists);
  offs_kernel<<<1, 1, 0, stream>>>(counts, offs, wl1, wl2);
  gather_conv_kernel<<<NTOK / 4, 256, 0, stream>>>(x, offs, lists, stok, xbs);

  if (big) {
    // both transposes in one exact-grid launch (Wt1, Wt2 separate)
    transpose_conv2_kernel<<<16384, 256, 0, stream>>>(W1, W2, Wt1, Wt2);
    ffn_kernel<256, 128, 4, 2, DDIM, HDIM, MAXWL1, false, true>
        <<<dim3((HDIM / 128) * MAXWL1), 512, 0, stream>>>(
            xbs, Wt1, b1, counts, offs, wl1, stok, Hs, nullptr, NEXP + 1);
    ffn_kernel<128, 256, 2, 4, HDIM, DDIM, MAXWL2, true, false>
        <<<dim3((DDIM / 256) * MAXWL2), 512, 0, stream>>>(
            Hs, Wt2, b2, counts, offs, wl2, stok, nullptr, out, NEXP + 2);
  } else {
    // fallback: sequential transposes sharing one Wt buffer (R10 exact)
    transpose_conv_kernel<<<dim3(HDIM / 64, DDIM / 64, NEXP), 256, 0, stream>>>(
        W1, Wt1, DDIM, HDIM);
    ffn_kernel<256, 128, 4, 2, DDIM, HDIM, MAXWL1, false, true>
        <<<dim3((HDIM / 128) * MAXWL1), 512, 0, stream>>>(
            xbs, Wt1, b1, counts, offs, wl1, stok, Hs, nullptr, NEXP + 1);
    transpose_conv_kernel<<<dim3(DDIM / 64, HDIM / 64, NEXP), 256, 0, stream>>>(
        W2, Wt1, HDIM, DDIM);
    ffn_kernel<128, 256, 2, 4, HDIM, DDIM, MAXWL2, true, false>
        <<<dim3((DDIM / 256) * MAXWL2), 512, 0, stream>>>(
            Hs, Wt1, b2, counts, offs, wl2, stok, nullptr, out, NEXP + 2);
  }
}

// Round 17
// 434.002 us; speedup vs baseline: 2.3875x; 1.0744x over previous
//
#include <hip/hip_runtime.h>
#include <hip/hip_bf16.h>
#include <stdint.h>

#define NTOK 8192
#define DDIM 1024
#define HDIM 4096
#define NEXP 8
#define MAXWL1 48   // BM=256 work-list
#define MAXWL2 72   // BM=128 work-list
#define FFN1_GRID ((HDIM / 128) * MAXWL1)   // 1536

typedef __attribute__((ext_vector_type(4))) float f32x4;
typedef __attribute__((ext_vector_type(8))) short s16x8;
typedef __attribute__((ext_vector_type(8))) unsigned short u16x8;

__device__ __forceinline__ unsigned short f2bf(float f) {
  union { float f; unsigned int u; } v; v.f = f;
  unsigned int u = v.u;
  u += 0x7FFFu + ((u >> 16) & 1u);   // round-to-nearest-even
  return (unsigned short)(u >> 16);
}

typedef __attribute__((address_space(3))) unsigned char lds_u8;
typedef const __attribute__((address_space(1))) unsigned char glb_u8;

__device__ __forceinline__ void load_lds16(const void* g, void* l) {
  __builtin_amdgcn_global_load_lds((glb_u8*)g, (lds_u8*)l, 16, 0, 0);
}

// ---------------- gate + top-1 routing ----------------
__global__ __launch_bounds__(256) void gate_kernel(
    const float* __restrict__ x, const float* __restrict__ Wg,
    const float* __restrict__ bg, int* __restrict__ counts,
    int* __restrict__ lists) {
  const int lane = threadIdx.x & 63;
  const int tok = blockIdx.x * 4 + (threadIdx.x >> 6);
  const float* xr = x + (size_t)tok * DDIM;
  double acc[NEXP];
#pragma unroll
  for (int e = 0; e < NEXP; ++e) acc[e] = 0.0;
#pragma unroll 4
  for (int it = 0; it < DDIM / 64; ++it) {
    const int d = it * 64 + lane;
    const float xv = xr[d];
    const f32x4 w0 = *(const f32x4*)(Wg + (size_t)d * NEXP);
    const f32x4 w1 = *(const f32x4*)(Wg + (size_t)d * NEXP + 4);
#pragma unroll
    for (int j = 0; j < 4; ++j) {
      acc[j]     += (double)xv * (double)w0[j];
      acc[4 + j] += (double)xv * (double)w1[j];
    }
  }
#pragma unroll
  for (int e = 0; e < NEXP; ++e) {
    double v = acc[e];
#pragma unroll
    for (int off = 32; off > 0; off >>= 1) v += __shfl_xor(v, off, 64);
    acc[e] = v;
  }
  if (lane == 0) {
    int best = 0;
    double bv = acc[0] + (double)bg[0];
#pragma unroll
    for (int e = 1; e < NEXP; ++e) {
      const double v = acc[e] + (double)bg[e];
      if (v > bv) { bv = v; best = e; }   // strict > : first max wins (np argmax)
    }
    const int pos = atomicAdd(&counts[best], 1);
    lists[best * NTOK + pos] = tok;
  }
}

// ---- prefix sum + two work-lists: wl1 (BM=256), wl2 (BM=128) ----
__global__ void offs_kernel(const int* __restrict__ counts, int* __restrict__ offs,
                            int* __restrict__ wl1, int* __restrict__ wl2) {
  int s = 0;
#pragma unroll
  for (int e = 0; e < NEXP; ++e) { offs[e] = s; s += counts[e]; }
  offs[NEXP] = s;
  int n1 = 0, n2 = 0;
  for (int e = 0; e < NEXP; ++e) {
    const int nb1 = (counts[e] + 255) >> 8;
    for (int b = 0; b < nb1; ++b) wl1[n1++] = (e << 20) | b;
    const int nb2 = (counts[e] + 127) >> 7;
    for (int b = 0; b < nb2; ++b) wl2[n2++] = (e << 20) | b;
  }
  offs[NEXP + 1] = n1;
  offs[NEXP + 2] = n2;
}

// -- transpose 64x64 tile body (R10 v2, caller-provided LDS [64][66]) --
__device__ __forceinline__ void transpose_tile(
    const float* __restrict__ ine, unsigned short* __restrict__ oute,
    int R, int C, int c0, int r0, int t, unsigned short* Tb) {
  const int tr = t >> 4, tc4 = (t & 15) * 4;
#pragma unroll
  for (int p = 0; p < 4; ++p) {
    const int r = tr + p * 16;
    const f32x4 v = *(const f32x4*)(ine + (size_t)(r0 + r) * C + c0 + tc4);
#pragma unroll
    for (int j = 0; j < 4; ++j) Tb[r * 66 + tc4 + j] = f2bf(v[j]);
  }
  __syncthreads();
  const int cc = t >> 3, rr8 = (t & 7) * 8;
#pragma unroll
  for (int p = 0; p < 2; ++p) {
    const int c = cc + p * 32;
    u16x8 o;
#pragma unroll
    for (int j = 0; j < 8; ++j) o[j] = Tb[(rr8 + j) * 66 + c];
    *(u16x8*)(oute + (size_t)(c0 + c) * R + r0 + rr8) = o;
  }
}

// -- standalone single-weight transpose (fallback path) --
__global__ __launch_bounds__(256) void transpose_conv_kernel(
    const float* __restrict__ in, unsigned short* __restrict__ out,
    int R, int C) {
  __shared__ __align__(16) unsigned short T[64 * 66];
  const int e = blockIdx.z;
  transpose_tile(in + (size_t)e * R * C, out + (size_t)e * C * R, R, C,
                 blockIdx.x * 64, blockIdx.y * 64, threadIdx.x, T);
}

// -- merged: gather(+conv) tokens  ||  W1 transpose  (independent work) --
// bid < NTOK/8: gather 8 tokens (1/wave). else: 2 transpose tiles (256 thr each).
__global__ __launch_bounds__(512) void gather_w1t_kernel(
    const float* __restrict__ x, const int* __restrict__ offs,
    const int* __restrict__ lists, int* __restrict__ stok,
    unsigned short* __restrict__ xbs, const float* __restrict__ W1,
    unsigned short* __restrict__ Wt1) {
  __shared__ __align__(16) unsigned short TT[2][64 * 66];
  const int bid = blockIdx.x;
  const int tid = threadIdx.x;
  if (bid < NTOK / 8) {
    const int p = bid * 8 + (tid >> 6);
    const int lane = tid & 63;
    int e = 0;
#pragma unroll
    for (int k = 1; k < NEXP; ++k) e += (p >= offs[k]) ? 1 : 0;
    const int tok = lists[e * NTOK + (p - offs[e])];
    if (lane == 0) stok[p] = tok;
    const float* src = x + (size_t)tok * DDIM + lane * 16;
    unsigned short* dst = xbs + (size_t)p * DDIM + lane * 16;
#pragma unroll
    for (int q = 0; q < 2; ++q) {
      const f32x4 a = *(const f32x4*)(src + q * 8);
      const f32x4 b = *(const f32x4*)(src + q * 8 + 4);
      u16x8 o;
#pragma unroll
      for (int j = 0; j < 4; ++j) { o[j] = f2bf(a[j]); o[4 + j] = f2bf(b[j]); }
      *(u16x8*)(dst + q * 8) = o;
    }
  } else {
    const int id = (bid - NTOK / 8) * 2 + (tid >> 8);   // W1: R=1024, C=4096
    const int t = tid & 255;
    const int e = id >> 10, rem = id & 1023;
    const int cb = rem & 63, rb = rem >> 6;
    transpose_tile(W1 + (size_t)e * DDIM * HDIM, Wt1 + (size_t)e * HDIM * DDIM,
                   DDIM, HDIM, cb * 64, rb * 64, t, TT[tid >> 8]);
  }
}

// ---- grouped-GEMM body (R10 exact): ring-2, depth-1, 0-conflict swizzle ----
template <int BM, int BN, int WM, int WN, int K, int N, int MAXWLT,
          bool COLFAST, bool FUSE1>
__device__ __forceinline__ void ffn_body(
    int d, const unsigned short* __restrict__ A,
    const unsigned short* __restrict__ Bt, const float* __restrict__ bias,
    const int* __restrict__ counts, const int* __restrict__ offs,
    const int* __restrict__ wl, const int* __restrict__ stok,
    unsigned short* __restrict__ outb, float* __restrict__ outf, int nwl_idx,
    unsigned short* As0, unsigned short* Bs0,
    unsigned short* As1, unsigned short* Bs1) {
  constexpr int MF = BM / (WM * 16);   // 4
  constexpr int NF = BN / (WN * 16);   // 4
  constexpr int ISS_A = BM / 128;
  constexpr int ISS_B = BN / 128;
  constexpr int NT = K / 32;
  constexpr int NCB = N / BN;
  constexpr int NWG = NCB * MAXWLT;
  static_assert((NWG & 7) == 0 && (NT & 1) == 0 && NT >= 4, "");
  static_assert(WM * WN == 8, "8 waves");

  const int logical = (d & 7) * (NWG / 8) + (d >> 3);  // XCD chunking
  int cb, wli;
  if constexpr (COLFAST) { cb = logical % NCB; wli = logical / NCB; }
  else                   { cb = logical / MAXWLT; wli = logical % MAXWLT; }
  if (wli >= offs[nwl_idx]) return;
  const int col0 = cb * BN;
  const int wle = wl[wli];
  const int e = wle >> 20;
  const int bx = wle & 0xFFFFF;
  const int cnt = counts[e];
  const int row0 = offs[e] + bx * BM;

  const int tid = threadIdx.x;
  const int lane = tid & 63;
  const int w = tid >> 6;
  const int wm = w / WN;
  const int wn = w % WN;
  const int fr = lane & 15;
  const int fj = lane >> 4;

  // staging: thread -> LDS row i*128+(tid>>2), 16B-slot tid&3;
  // source slot pre-swizzled by ^((row>>1)&3) = ^((tid>>3)&3)  [R9-verified]
  const int swsrc = ((tid & 3) ^ ((tid >> 3) & 3)) * 8;   // ushort offset
  const int rb = tid >> 2;
  const unsigned short* srcA[ISS_A];
#pragma unroll
  for (int i = 0; i < ISS_A; ++i) {
    int gr = row0 + i * 128 + rb;
    if (gr > NTOK - 1) gr = NTOK - 1;   // clamp: garbage rows masked in epilogue
    srcA[i] = A + (size_t)gr * K + swsrc;
  }
  const unsigned short* Bte = Bt + (size_t)e * N * K;
  const unsigned short* srcB[ISS_B];
#pragma unroll
  for (int i = 0; i < ISS_B; ++i)
    srcB[i] = Bte + (size_t)(col0 + i * 128 + rb) * K + swsrc;

  // ds_read swizzled 16B-slot (per-lane constant): fj ^ ((fr>>1)&3)
  const int js = (fj ^ ((fr >> 1) & 3)) * 8;

  f32x4 acc[MF][NF];
#pragma unroll
  for (int m = 0; m < MF; ++m)
#pragma unroll
    for (int n = 0; n < NF; ++n) acc[m][n] = f32x4{0.f, 0.f, 0.f, 0.f};

  auto stage = [&](unsigned short* dA, unsigned short* dB, int kel) {
#pragma unroll
    for (int i = 0; i < ISS_A; ++i)
      load_lds16(srcA[i] + kel, dA + i * 4096 + tid * 8);
#pragma unroll
    for (int i = 0; i < ISS_B; ++i)
      load_lds16(srcB[i] + kel, dB + i * 4096 + tid * 8);
  };

  auto phase = [&](const unsigned short* pA, const unsigned short* pB,
                   unsigned short* nA, unsigned short* nB, int knext,
                   bool do_stage) {
    asm volatile("s_waitcnt vmcnt(0)" ::: "memory");  // current tile landed
    __builtin_amdgcn_s_barrier();
    asm volatile("" ::: "memory");
    // read whole tile into registers BEFORE staging next (no alias waits)
    s16x8 af[MF], bf[NF];
#pragma unroll
    for (int m = 0; m < MF; ++m)
      af[m] = *(const s16x8*)(pA + (wm * MF * 16 + m * 16 + fr) * 32 + js);
#pragma unroll
    for (int n = 0; n < NF; ++n)
      bf[n] = *(const s16x8*)(pB + (wn * NF * 16 + n * 16 + fr) * 32 + js);
    if (do_stage) stage(nA, nB, knext);   // flies under MFMA + co-resident block
    __builtin_amdgcn_s_setprio(1);
#pragma unroll
    for (int m = 0; m < MF; ++m)
#pragma unroll
      for (int n = 0; n < NF; ++n)
        acc[m][n] = __builtin_amdgcn_mfma_f32_16x16x32_bf16(af[m], bf[n],
                                                            acc[m][n], 0, 0, 0);
    __builtin_amdgcn_s_setprio(0);
  };

  stage(As0, Bs0, 0);   // prologue
#pragma unroll 1
  for (int t = 0; t < NT - 2; t += 2) {
    phase(As0, Bs0, As1, Bs1, (t + 1) * 32, true);
    phase(As1, Bs1, As0, Bs0, (t + 2) * 32, true);
  }
  phase(As0, Bs0, As1, Bs1, (NT - 1) * 32, true);
  phase(As1, Bs1, nullptr, nullptr, 0, false);

  // epilogue
#pragma unroll
  for (int n = 0; n < NF; ++n) {
    const int col = col0 + wn * NF * 16 + n * 16 + fr;
    const float bv = bias[e * N + col];
#pragma unroll
    for (int m = 0; m < MF; ++m) {
#pragma unroll
      for (int j = 0; j < 4; ++j) {
        const int rl = wm * MF * 16 + m * 16 + fj * 4 + j;
        if (bx * BM + rl < cnt) {
          if constexpr (FUSE1) {
            outb[(size_t)(row0 + rl) * N + col] = f2bf(fmaxf(acc[m][n][j] + bv, 0.f));
          } else {
            outf[(size_t)stok[row0 + rl] * N + col] = acc[m][n][j] + bv;
          }
        }
      }
    }
  }
}

// -- merged: ffn1 blocks first, then W2-transpose blocks (independent work) --
// Transpose scratch overlays As0/As1 (48KB block footprint -> 3 blk/CU, so
// mixed CUs host 2 ffn + 1 transpose block; W2T's HBM traffic rides under
// ffn1's L2-dominated staging).
__global__ __launch_bounds__(512, 4) void ffn1_w2t_kernel(
    const unsigned short* __restrict__ A, const unsigned short* __restrict__ Bt,
    const float* __restrict__ bias, const int* __restrict__ counts,
    const int* __restrict__ offs, const int* __restrict__ wl,
    const int* __restrict__ stok, unsigned short* __restrict__ Hs,
    const float* __restrict__ W2, unsigned short* __restrict__ Wt2) {
  __shared__ __align__(16) unsigned short As0[256 * 32], Bs0[128 * 32];
  __shared__ __align__(16) unsigned short As1[256 * 32], Bs1[128 * 32];
  const int bid = blockIdx.x;
  if (bid < FFN1_GRID) {
    ffn_body<256, 128, 4, 2, DDIM, HDIM, MAXWL1, false, true>(
        bid, A, Bt, bias, counts, offs, wl, stok, Hs, nullptr, NEXP + 1,
        As0, Bs0, As1, Bs1);
  } else {
    const int id = (bid - FFN1_GRID) * 2 + (threadIdx.x >> 8);  // W2: R=4096,C=1024
    const int t = threadIdx.x & 255;
    const int e = id >> 10, rem = id & 1023;
    const int cb = rem & 15, rb = rem >> 4;
    transpose_tile(W2 + (size_t)e * HDIM * DDIM, Wt2 + (size_t)e * DDIM * HDIM,
                   HDIM, DDIM, cb * 64, rb * 64, t,
                   (threadIdx.x >= 256) ? As1 : As0);
  }
}

// -- standalone ffn2 --
template <int BM, int BN, int WM, int WN, int K, int N, int MAXWLT,
          bool COLFAST, bool FUSE1>
__global__ __launch_bounds__(512, 4) void ffn_kernel(
    const unsigned short* __restrict__ A, const unsigned short* __restrict__ Bt,
    const float* __restrict__ bias, const int* __restrict__ counts,
    const int* __restrict__ offs, const int* __restrict__ wl,
    const int* __restrict__ stok, unsigned short* __restrict__ outb,
    float* __restrict__ outf, int nwl_idx) {
  __shared__ __align__(16) unsigned short As0[BM * 32], Bs0[BN * 32];
  __shared__ __align__(16) unsigned short As1[BM * 32], Bs1[BN * 32];
  ffn_body<BM, BN, WM, WN, K, N, MAXWLT, COLFAST, FUSE1>(
      blockIdx.x, A, Bt, bias, counts, offs, wl, stok, outb, outf, nwl_idx,
      As0, Bs0, As1, Bs1);
}

extern "C" void kernel_launch(void* const* d_in, const int* in_sizes, int n_in,
                              void* d_out, int out_size, void* d_ws, size_t ws_size,
                              hipStream_t stream) {
  (void)in_sizes; (void)n_in; (void)out_size;
  const float* x  = (const float*)d_in[0];
  const float* Wg = (const float*)d_in[1];
  const float* bg = (const float*)d_in[2];
  const float* W1 = (const float*)d_in[3];
  const float* b1 = (const float*)d_in[4];
  const float* W2 = (const float*)d_in[5];
  const float* b2 = (const float*)d_in[6];
  float* out = (float*)d_out;

  char* ws = (char*)d_ws;
  const size_t OFF_CNT = 0;                                    // 8 ints
  const size_t OFF_OFF = 128;                                  // offs[0..10]
  const size_t OFF_WL1 = 256;                                  // MAXWL1 ints
  const size_t OFF_WL2 = 256 + MAXWL1 * 4;                     // MAXWL2 ints
  const size_t OFF_LST = 1024;                                 // E*NTOK ints (256 KB)
  const size_t OFF_STK = OFF_LST + (size_t)NEXP * NTOK * 4;    // NTOK ints
  const size_t OFF_XBS = OFF_STK + (size_t)NTOK * 4;           // NTOK*D bf16 (16 MB)
  const size_t OFF_HS  = OFF_XBS + (size_t)NTOK * DDIM * 2;    // NTOK*H bf16 (64 MB)
  const size_t OFF_WT1 = OFF_HS + (size_t)NTOK * HDIM * 2;     // E*H*D bf16 (64 MB)
  const size_t SZ_W    = (size_t)NEXP * DDIM * HDIM * 2;
  const size_t OFF_WT2 = OFF_WT1 + SZ_W;                       // E*D*H bf16 (64 MB)
  const size_t NEED_SMALL = OFF_WT1 + SZ_W;                    // shared Wt buffer
  const size_t NEED_BIG   = OFF_WT2 + SZ_W;                    // both Wt buffers
  if (ws_size < NEED_SMALL) return;
  const bool big = (ws_size >= NEED_BIG);

  int* counts = (int*)(ws + OFF_CNT);
  int* offs   = (int*)(ws + OFF_OFF);
  int* wl1    = (int*)(ws + OFF_WL1);
  int* wl2    = (int*)(ws + OFF_WL2);
  int* lists  = (int*)(ws + OFF_LST);
  int* stok   = (int*)(ws + OFF_STK);
  unsigned short* xbs = (unsigned short*)(ws + OFF_XBS);
  unsigned short* Hs  = (unsigned short*)(ws + OFF_HS);
  unsigned short* Wt1 = (unsigned short*)(ws + OFF_WT1);
  unsigned short* Wt2 = big ? (unsigned short*)(ws + OFF_WT2) : Wt1;

  hipMemsetAsync(counts, 0, 128, stream);
  gate_kernel<<<NTOK / 4, 256, 0, stream>>>(x, Wg, bg, counts, lists);
  offs_kernel<<<1, 1, 0, stream>>>(counts, offs, wl1, wl2);

  // merged: gather-conv || W1 transpose (independent)
  gather_w1t_kernel<<<NTOK / 8 + 4096, 512, 0, stream>>>(
      x, offs, lists, stok, xbs, W1, Wt1);

  if (big) {
    // merged: ffn1 || W2 transpose (independent; Wt2 separate buffer)
    ffn1_w2t_kernel<<<FFN1_GRID + 4096, 512, 0, stream>>>(
        xbs, Wt1, b1, counts, offs, wl1, stok, Hs, W2, Wt2);
  } else {
    ffn_kernel<256, 128, 4, 2, DDIM, HDIM, MAXWL1, false, true>
        <<<dim3(FFN1_GRID), 512, 0, stream>>>(
            xbs, Wt1, b1, counts, offs, wl1, stok, Hs, nullptr, NEXP + 1);
    transpose_conv_kernel<<<dim3(DDIM / 64, HDIM / 64, NEXP), 256, 0, stream>>>(
        W2, Wt1, HDIM, DDIM);
  }
  // ffn2: 128x256 tile, col-fastest (A-tile L2 reuse)
  ffn_kernel<128, 256, 2, 4, HDIM, DDIM, MAXWL2, true, false>
      <<<dim3((DDIM / 256) * MAXWL2), 512, 0, stream>>>(
          Hs, Wt2, b2, counts, offs, wl2, stok, nullptr, out, NEXP + 2);
}